// Round 5
// baseline (461.093 us; speedup 1.0000x reference)
//
#include <hip/hip_runtime.h>
#include <cstdint>

constexpr int B = 32, C = 256, H = 56, W = 56;
constexpr int HW = H * W;          // 3136
constexpr int WORDS = 8;           // 256 ci / 32
constexpr int TAPS = 9;
constexpr int WPC = TAPS * WORDS;  // 72
constexpr int PH = H + 2, PW = W + 2, PHW = PH * PW;  // 58x58
constexpr int RSTRIDE = 20;        // LDS res row stride in words (16 used + pad)

// ---------------------------------------------------------------------------
// Zero the pad ring of px (ws is re-poisoned to 0xAA before every launch).
// ---------------------------------------------------------------------------
__global__ __launch_bounds__(256) void pad_zero_kernel(uint32_t* __restrict__ px) {
    int idx = blockIdx.x * 256 + threadIdx.x;   // 32*228*8 = 58368 exact
    int wd = idx & 7;
    int r = idx >> 3;
    int ring = r % 228;
    int b = r / 228;
    int ph, pwp;
    if (ring < 58)       { ph = 0;              pwp = ring; }
    else if (ring < 116) { ph = 57;             pwp = ring - 58; }
    else if (ring < 172) { ph = 1 + (ring - 116); pwp = 0; }
    else                 { ph = 1 + (ring - 172); pwp = 57; }
    px[((size_t)(b * PH + ph) * PW + pwp) * WORDS + wd] = 0u;
}

// ---------------------------------------------------------------------------
// Pack x signs (interior only): thread = (b, wd, hw4); float4 loads (4 px) per
// channel plane, coalesced across lanes; sign via MSB extraction.
// ---------------------------------------------------------------------------
__global__ __launch_bounds__(256) void pack_x_kernel(const float* __restrict__ x,
                                                     uint32_t* __restrict__ px) {
    int idx = blockIdx.x * 256 + threadIdx.x;   // 32*8*784 = 200704 exact
    int hw4 = idx % 784;
    int r = idx / 784;
    int wd = r & 7;
    int b = r >> 3;
    const float4* xp = reinterpret_cast<const float4*>(x + ((size_t)b * C + wd * 32) * HW) + hw4;
    uint32_t w0 = 0, w1 = 0, w2 = 0, w3 = 0;
    #pragma unroll
    for (int i = 0; i < 32; ++i) {
        float4 v = xp[(size_t)i * (HW / 4)];
        w0 |= (__float_as_uint(v.x) >> 31) << i;
        w1 |= (__float_as_uint(v.y) >> 31) << i;
        w2 |= (__float_as_uint(v.z) >> 31) << i;
        w3 |= (__float_as_uint(v.w) >> 31) << i;
    }
    int hw = hw4 * 4;
    #pragma unroll
    for (int q = 0; q < 4; ++q) {
        int h = (hw + q) / W, w = (hw + q) - h * W;
        uint32_t val = (q == 0) ? w0 : (q == 1) ? w1 : (q == 2) ? w2 : w3;
        px[((size_t)(b * PH + h + 1) * PW + (w + 1)) * WORDS + wd] = val;
    }
}

// ---------------------------------------------------------------------------
// Pack w signs via ballot: one wave per (co, tap, 64-ci chunk).
// ---------------------------------------------------------------------------
__global__ __launch_bounds__(256) void pack_w_kernel(const float* __restrict__ wt,
                                                     uint32_t* __restrict__ pw) {
    int gid = blockIdx.x * 256 + threadIdx.x;   // C*9*4*64 = 589824 exact
    int lane = gid & 63;
    int wv = gid >> 6;
    int pr = wv & 3;
    int ct = wv >> 2;
    int tap = ct % 9;
    int co = ct / 9;
    int ci = pr * 64 + lane;
    float v = wt[((size_t)co * C + ci) * TAPS + tap];
    unsigned long long m = __ballot(v < 0.0f);
    if (lane == 0) {
        pw[(size_t)co * WPC + tap * WORDS + pr * 2]     = (uint32_t)m;
        pw[(size_t)co * WPC + tap * WORDS + pr * 2 + 1] = (uint32_t)(m >> 32);
    }
}

// ---------------------------------------------------------------------------
// Main conv, lane = output channel (co = (threadIdx>>6)*64 + lane).
// __launch_bounds__(256,4): 128-VGPR budget so the 72 weight words stay
// VGPR-resident for the whole kernel (round-4's VGPR=52 spill fix).
// px 3x3 window is wave-uniform -> scalar s_loads (K$, shared by 4 waves).
// Border correction wave-uniform from per-tap weight popcounts tp[t].
// Stores: 16-px chunks staged in LDS (stride-20 rows), then cooperative
// write-out where each 4-lane group emits one full 64B line of a co-row
// -> coalesced, WRITE_SIZE back to ~100 MB.
// ---------------------------------------------------------------------------
__global__ __launch_bounds__(256, 4) void bconv_kernel(const uint32_t* __restrict__ px,
                                                       const uint32_t* __restrict__ pw,
                                                       const float* __restrict__ bias,
                                                       float* __restrict__ out) {
    const int lane = threadIdx.x & 63;
    const int wid = threadIdx.x >> 6;
    const int co = wid * 64 + lane;
    const int hwbase = blockIdx.x * 64;     // 49 blocks exact
    const int b = blockIdx.y;

    __shared__ float res[256 * RSTRIDE];    // 20 KB

    // ---- weights -> 72 VGPRs, once ----
    uint32_t wreg[WPC];
    {
        const uint4* wp = reinterpret_cast<const uint4*>(pw + (size_t)co * WPC);
        #pragma unroll
        for (int i = 0; i < 18; ++i) {
            uint4 v = wp[i];
            wreg[i * 4 + 0] = v.x; wreg[i * 4 + 1] = v.y;
            wreg[i * 4 + 2] = v.z; wreg[i * 4 + 3] = v.w;
        }
    }
    uint32_t tp[TAPS];
    #pragma unroll
    for (int t = 0; t < TAPS; ++t) {
        uint32_t s = 0;
        #pragma unroll
        for (int k = 0; k < WORDS; ++k) s += __popc(wreg[t * WORDS + k]);
        tp[t] = s;
    }
    const float basep = 2304.0f + bias[co];

    #pragma unroll 1
    for (int chunk = 0; chunk < 4; ++chunk) {
        const int pbase = hwbase + chunk * 16;
        float o[16];
        #pragma unroll
        for (int q = 0; q < 16; ++q) {
            const int hw = pbase + q;
            const int h = hw / W;          // wave-uniform
            const int w = hw - h * W;      // wave-uniform
            const uint32_t* rp = px + ((size_t)(b * PH + h) * PW + w) * WORDS;
            uint32_t a0 = 0, a1 = 0, a2 = 0, a3 = 0;
            #pragma unroll
            for (int row = 0; row < 3; ++row) {
                const uint32_t* rr = rp + row * (PW * WORDS);  // 24 contiguous words
                #pragma unroll
                for (int c = 0; c < 3; ++c) {
                    const int t = row * 3 + c;
                    a0 += __popc(rr[c * 8 + 0] ^ wreg[t * 8 + 0]);
                    a1 += __popc(rr[c * 8 + 1] ^ wreg[t * 8 + 1]);
                    a2 += __popc(rr[c * 8 + 2] ^ wreg[t * 8 + 2]);
                    a3 += __popc(rr[c * 8 + 3] ^ wreg[t * 8 + 3]);
                    a0 += __popc(rr[c * 8 + 4] ^ wreg[t * 8 + 4]);
                    a1 += __popc(rr[c * 8 + 5] ^ wreg[t * 8 + 5]);
                    a2 += __popc(rr[c * 8 + 6] ^ wreg[t * 8 + 6]);
                    a3 += __popc(rr[c * 8 + 7] ^ wreg[t * 8 + 7]);
                }
            }
            const uint32_t total = (a0 + a1) + (a2 + a3);
            float base2 = basep;
            if (h == 0 || h == H - 1 || w == 0 || w == W - 1) {   // wave-uniform
                uint32_t s = 0;
                int ninv = 0;
                #pragma unroll
                for (int t = 0; t < TAPS; ++t) {
                    const int dh = t / 3, dw = t % 3;
                    const bool inv = (h == 0 && dh == 0) || (h == H - 1 && dh == 2) ||
                                     (w == 0 && dw == 0) || (w == W - 1 && dw == 2);
                    if (inv) { s += tp[t]; ++ninv; }
                }
                base2 = basep + (float)(2 * (int)s - 256 * ninv);
            }
            o[q] = fmaf(-2.0f, (float)(int)total, base2);
        }

        __syncthreads();   // previous chunk's LDS reads done
        #pragma unroll
        for (int qq = 0; qq < 16; qq += 4) {
            *reinterpret_cast<float4*>(&res[co * RSTRIDE + qq]) =
                make_float4(o[qq], o[qq + 1], o[qq + 2], o[qq + 3]);
        }
        __syncthreads();   // res fully written

        // cooperative coalesced write-out: 4 lanes x float4 = one 64B line/row
        #pragma unroll
        for (int i = 0; i < 4; ++i) {
            const int t = threadIdx.x;
            const int co2 = (i * 256 + t) >> 2;
            const int pp = (t & 3) << 2;
            float4 v = *reinterpret_cast<const float4*>(&res[co2 * RSTRIDE + pp]);
            *reinterpret_cast<float4*>(out + ((size_t)b * C + co2) * HW + pbase + pp) = v;
        }
    }
}

extern "C" void kernel_launch(void* const* d_in, const int* in_sizes, int n_in,
                              void* d_out, int out_size, void* d_ws, size_t ws_size,
                              hipStream_t stream) {
    const float* x = (const float*)d_in[0];
    const float* wt = (const float*)d_in[1];
    const float* bias = (const float*)d_in[2];
    float* out = (float*)d_out;

    uint32_t* px = (uint32_t*)d_ws;                    // 32*58*58*8*4 = 3,444,736 B
    uint32_t* pw = px + (size_t)B * PHW * WORDS;       // + 73,728 B

    pad_zero_kernel<<<(B * 228 * WORDS) / 256, 256, 0, stream>>>(px);
    pack_x_kernel<<<(B * WORDS * (HW / 4)) / 256, 256, 0, stream>>>(x, px);
    pack_w_kernel<<<(C * TAPS * 4 * 64) / 256, 256, 0, stream>>>(wt, pw);

    dim3 grid(HW / 64, B);
    bconv_kernel<<<grid, 256, 0, stream>>>(px, pw, bias, out);
}

// Round 6
// 360.429 us; speedup vs baseline: 1.2793x; 1.2793x over previous
//
#include <hip/hip_runtime.h>
#include <cstdint>

constexpr int B = 32, C = 256, H = 56, W = 56;
constexpr int HW = H * W;          // 3136
constexpr int WORDS = 8;           // 256 ci / 32
constexpr int TAPS = 9;
constexpr int WPC = TAPS * WORDS;  // 72
constexpr int PH = H + 2, PW = W + 2, PHW = PH * PW;  // 58x58

// ---------------------------------------------------------------------------
// Zero the pad ring of px (ws re-poisoned to 0xAA before every launch).
// ---------------------------------------------------------------------------
__global__ __launch_bounds__(256) void pad_zero_kernel(uint32_t* __restrict__ px) {
    int idx = blockIdx.x * 256 + threadIdx.x;   // 32*228*8 = 58368 exact
    int wd = idx & 7;
    int r = idx >> 3;
    int ring = r % 228;
    int b = r / 228;
    int ph, pwp;
    if (ring < 58)       { ph = 0;              pwp = ring; }
    else if (ring < 116) { ph = 57;             pwp = ring - 58; }
    else if (ring < 172) { ph = 1 + (ring - 116); pwp = 0; }
    else                 { ph = 1 + (ring - 172); pwp = 57; }
    px[((size_t)(b * PH + ph) * PW + pwp) * WORDS + wd] = 0u;
}

// ---------------------------------------------------------------------------
// Pack x signs (interior). Thread map: wd fastest within 8-lane groups, so the
// 8 words of one pixel record are written contiguously (32B) per group ->
// coalesced writes; reads per instr = 8 channel-planes x 128B segments.
// ---------------------------------------------------------------------------
__global__ __launch_bounds__(256) void pack_x_kernel(const float* __restrict__ x,
                                                     uint32_t* __restrict__ px) {
    int idx = blockIdx.x * 256 + threadIdx.x;   // 32*784*8 = 200704 exact
    int wd = idx & 7;
    int r = idx >> 3;              // b*784 + hw4
    int hw4 = r % 784;
    int b = r / 784;
    const float4* xp = reinterpret_cast<const float4*>(x + ((size_t)b * C + wd * 32) * HW) + hw4;
    uint32_t w0 = 0, w1 = 0, w2 = 0, w3 = 0;
    #pragma unroll
    for (int i = 0; i < 32; ++i) {
        float4 v = xp[(size_t)i * (HW / 4)];
        w0 |= (__float_as_uint(v.x) >> 31) << i;
        w1 |= (__float_as_uint(v.y) >> 31) << i;
        w2 |= (__float_as_uint(v.z) >> 31) << i;
        w3 |= (__float_as_uint(v.w) >> 31) << i;
    }
    // 4 consecutive pixels, all in one row (W=56, groups 4-aligned)
    int hw = hw4 * 4;
    int h = hw / W, w = hw - h * W;
    uint32_t* dst = px + ((size_t)(b * PH + h + 1) * PW + (w + 1)) * WORDS + wd;
    dst[0]  = w0;
    dst[8]  = w1;
    dst[16] = w2;
    dst[24] = w3;
}

// ---------------------------------------------------------------------------
// Pack w signs via ballot: one wave per (co, tap, 64-ci chunk).
// ---------------------------------------------------------------------------
__global__ __launch_bounds__(256) void pack_w_kernel(const float* __restrict__ wt,
                                                     uint32_t* __restrict__ pw) {
    int gid = blockIdx.x * 256 + threadIdx.x;   // C*9*4*64 = 589824 exact
    int lane = gid & 63;
    int wv = gid >> 6;
    int pr = wv & 3;
    int ct = wv >> 2;
    int tap = ct % 9;
    int co = ct / 9;
    int ci = pr * 64 + lane;
    float v = wt[((size_t)co * C + ci) * TAPS + tap];
    unsigned long long m = __ballot(v < 0.0f);
    if (lane == 0) {
        pw[(size_t)co * WPC + tap * WORDS + pr * 2]     = (uint32_t)m;
        pw[(size_t)co * WPC + tap * WORDS + pr * 2 + 1] = (uint32_t)(m >> 32);
    }
}

// ---------------------------------------------------------------------------
// Border-correction tables:
//  ctab[co][8] = {Stop, Sbot, Sleft, Sright, tp0, tp2, tp6, tp8} (tap popcounts)
//  btab[co]    = 2304 + bias[co]
// out = btab - 256*ninv + 2*S - 2*popc_all, S = sum of tp over invalid taps.
// ---------------------------------------------------------------------------
__global__ __launch_bounds__(256) void ctab_kernel(const uint32_t* __restrict__ pw,
                                                   const float* __restrict__ bias,
                                                   uint32_t* __restrict__ ctab,
                                                   float* __restrict__ btab) {
    int co = threadIdx.x;          // single 256-thread block
    uint32_t tp[TAPS];
    #pragma unroll
    for (int t = 0; t < TAPS; ++t) {
        uint32_t s = 0;
        #pragma unroll
        for (int k = 0; k < WORDS; ++k) s += __popc(pw[(size_t)co * WPC + t * 8 + k]);
        tp[t] = s;
    }
    uint32_t* c8 = ctab + (size_t)co * 8;
    c8[0] = tp[0] + tp[1] + tp[2];   // top row invalid   (h==0)
    c8[1] = tp[6] + tp[7] + tp[8];   // bottom row invalid(h==55)
    c8[2] = tp[0] + tp[3] + tp[6];   // left col invalid  (w==0)
    c8[3] = tp[2] + tp[5] + tp[8];   // right col invalid (w==55)
    c8[4] = tp[0]; c8[5] = tp[2]; c8[6] = tp[6]; c8[7] = tp[8];
    btab[co] = 2304.0f + bias[co];
}

// ---------------------------------------------------------------------------
// Main conv. 1-wave blocks; lane = horizontal PIXEL PAIR (hw, hw+1); the
// shared 3x4 window (96 words) lives in VGPRs (round-2-proven codegen).
// Weight row address is uniform BY CONSTRUCTION (blockIdx/loop only) ->
// s_load into SGPRs, consumed as v_xor(s,v)+v_bcnt accumulate. 2 pixels/lane
// halves the per-j scalar-fetch stall fraction. Border algebra folded in via
// uniform ctab row + per-lane masks (pixel a: only-left-edge; b: only-right).
// Stores: float2/lane = 512B contiguous per wave, full lines.
// ---------------------------------------------------------------------------
__global__ __launch_bounds__(64, 3) void bconv_kernel(const uint32_t* __restrict__ px,
                                                      const uint32_t* __restrict__ pw,
                                                      const uint32_t* __restrict__ ctab,
                                                      const float* __restrict__ btab,
                                                      float* __restrict__ out) {
    const int lane = threadIdx.x;
    const int cobase = blockIdx.y * 64;        // uniform (grid.y = 4)
    const int b = blockIdx.z;
    int hw = blockIdx.x * 128 + lane * 2;      // grid.x = 25; last block half-masked
    const bool active = (hw < HW);
    if (!active) hw = HW - 2;
    const int h = hw / W;
    const int w = hw - h * W;                  // even; pairs never straddle rows

    // window rows h..h+2, cols w..w+3 (padded coords), 3x4x8 words in VGPRs
    uint32_t win[3][4][8];
    #pragma unroll
    for (int r = 0; r < 3; ++r) {
        const uint4* rp = reinterpret_cast<const uint4*>(
            px + ((size_t)(b * PH + h + r) * PW + w) * WORDS);
        #pragma unroll
        for (int c = 0; c < 4; ++c) {
            uint4 lo = rp[c * 2], hi = rp[c * 2 + 1];
            win[r][c][0] = lo.x; win[r][c][1] = lo.y; win[r][c][2] = lo.z; win[r][c][3] = lo.w;
            win[r][c][4] = hi.x; win[r][c][5] = hi.y; win[r][c][6] = hi.z; win[r][c][7] = hi.w;
        }
    }

    // border masks: pixel a = (h,w) [w even -> only possible left edge];
    //               pixel b = (h,w+1) [only possible right edge]
    const bool bh0 = (h == 0), bh1 = (h == H - 1);
    const bool bw0 = (w == 0), bw1 = (w + 1 == W - 1);
    const uint32_t mT = bh0 ? ~0u : 0u;
    const uint32_t mB = bh1 ? ~0u : 0u;
    const uint32_t mLa = bw0 ? ~0u : 0u;
    const uint32_t mRb = bw1 ? ~0u : 0u;
    const uint32_t mCa = (mT | mB) & mLa;
    const uint32_t mCb = (mT | mB) & mRb;
    const int nva = 3 * ((int)bh0 + (int)bh1 + (int)bw0) - (mCa ? 1 : 0);
    const int nvb = 3 * ((int)bh0 + (int)bh1 + (int)bw1) - (mCb ? 1 : 0);
    const float fa = -256.0f * (float)nva;
    const float fb = -256.0f * (float)nvb;

    float* op = out + ((size_t)b * C + cobase) * HW + hw;

    #pragma unroll 1
    for (int j = 0; j < 64; ++j) {
        const uint32_t* wr = pw + (size_t)(cobase + j) * WPC;    // uniform -> s_load
        uint32_t a0 = 0, a1 = 0, a2 = 0, a3 = 0;
        uint32_t b0 = 0, b1 = 0, b2 = 0, b3 = 0;
        #pragma unroll
        for (int r = 0; r < 3; ++r) {
            #pragma unroll
            for (int c = 0; c < 3; ++c) {
                const int t = r * 3 + c;
                a0 += __popc(win[r][c][0]     ^ wr[t * 8 + 0]);
                a1 += __popc(win[r][c][1]     ^ wr[t * 8 + 1]);
                a2 += __popc(win[r][c][2]     ^ wr[t * 8 + 2]);
                a3 += __popc(win[r][c][3]     ^ wr[t * 8 + 3]);
                a0 += __popc(win[r][c][4]     ^ wr[t * 8 + 4]);
                a1 += __popc(win[r][c][5]     ^ wr[t * 8 + 5]);
                a2 += __popc(win[r][c][6]     ^ wr[t * 8 + 6]);
                a3 += __popc(win[r][c][7]     ^ wr[t * 8 + 7]);
                b0 += __popc(win[r][c + 1][0] ^ wr[t * 8 + 0]);
                b1 += __popc(win[r][c + 1][1] ^ wr[t * 8 + 1]);
                b2 += __popc(win[r][c + 1][2] ^ wr[t * 8 + 2]);
                b3 += __popc(win[r][c + 1][3] ^ wr[t * 8 + 3]);
                b0 += __popc(win[r][c + 1][4] ^ wr[t * 8 + 4]);
                b1 += __popc(win[r][c + 1][5] ^ wr[t * 8 + 5]);
                b2 += __popc(win[r][c + 1][6] ^ wr[t * 8 + 6]);
                b3 += __popc(win[r][c + 1][7] ^ wr[t * 8 + 7]);
            }
        }
        const uint32_t ta = (a0 + a1) + (a2 + a3);
        const uint32_t tb = (b0 + b1) + (b2 + b3);

        const uint32_t* c8 = ctab + (size_t)(cobase + j) * 8;    // uniform -> s_load
        const uint32_t sv = (c8[0] & mT) + (c8[1] & mB);
        const uint32_t Sa = sv + (c8[2] & mLa) - ((bh0 ? c8[4] : c8[6]) & mCa);
        const uint32_t Sb = sv + (c8[3] & mRb) - ((bh0 ? c8[5] : c8[7]) & mCb);
        const float bb = btab[cobase + j];                        // uniform
        const float oa = fmaf(-2.0f, (float)((int)ta - (int)Sa), bb + fa);
        const float ob = fmaf(-2.0f, (float)((int)tb - (int)Sb), bb + fb);
        if (active)
            *reinterpret_cast<float2*>(op + (size_t)j * HW) = make_float2(oa, ob);
    }
}

extern "C" void kernel_launch(void* const* d_in, const int* in_sizes, int n_in,
                              void* d_out, int out_size, void* d_ws, size_t ws_size,
                              hipStream_t stream) {
    const float* x = (const float*)d_in[0];
    const float* wt = (const float*)d_in[1];
    const float* bias = (const float*)d_in[2];
    float* out = (float*)d_out;

    uint32_t* px = (uint32_t*)d_ws;                    // 861184 w = 3,444,736 B
    uint32_t* pw = px + (size_t)B * PHW * WORDS;       // 18432 w
    uint32_t* ctab = pw + (size_t)C * WPC;             // 2048 w
    float* btab = (float*)(ctab + (size_t)C * 8);      // 256 f

    pad_zero_kernel<<<(B * 228 * WORDS) / 256, 256, 0, stream>>>(px);
    pack_x_kernel<<<(B * WORDS * (HW / 4)) / 256, 256, 0, stream>>>(x, px);
    pack_w_kernel<<<(C * TAPS * 4 * 64) / 256, 256, 0, stream>>>(wt, pw);
    ctab_kernel<<<1, 256, 0, stream>>>(pw, bias, ctab, btab);

    dim3 grid((HW / 2 + 63) / 64, C / 64, B);          // (25, 4, 32)
    bconv_kernel<<<grid, 64, 0, stream>>>(px, pw, ctab, btab, out);
}